// Round 9
// baseline (366.084 us; speedup 1.0000x reference)
//
#include <hip/hip_runtime.h>

typedef unsigned short ushort_t;
typedef short s16x8 __attribute__((ext_vector_type(8)));
typedef float f32x4 __attribute__((ext_vector_type(4)));
typedef unsigned int uint2_t __attribute__((ext_vector_type(2)));
typedef unsigned int uint4_t __attribute__((ext_vector_type(4)));

#define KDIM 256
#define BK 64
#define LDST 72          // 64 + 8 pad (bf16 elems)
#define LV_TOTAL 21760
#define HL 696320        // 21760 * 32 elems per (batch,head) plane
#define NQ 8000
#define VM_TILES2 680    // 174080 / 256 (256-row tiles, block-claimed, per half)
#define QOA_BLOCKS 96    // 32 m-tiles (256 rows) x 3 n-tiles (128 cols)
#define VPROJ_BLOCKS 672 // oversubscribed claim-balanced (512 resident slots)

__device__ inline unsigned short f2b(float f) {
  union { float f; unsigned u; } v; v.f = f;
  return (unsigned short)((v.u + 0x7fffu + ((v.u >> 16) & 1u)) >> 16);  // RNE
}
__device__ inline float b2f(unsigned short h) {
  union { unsigned u; float f; } v; v.u = ((unsigned)h) << 16;
  return v.f;
}
// round-half-up bf16 pair pack: 2x v_add_u32 + 1x v_perm_b32
__device__ inline unsigned pack_bf16x2(float lo, float hi) {
  union { float f; unsigned u; } a, b;
  a.f = lo; b.f = hi;
  return __builtin_amdgcn_perm(b.u + 0x8000u, a.u + 0x8000u, 0x07060302u);
}

// ---- weight prep: transpose to [n][k] + bf16 convert; zero tile counters ----
__global__ __launch_bounds__(256) void prep_weights(
    const float* __restrict__ w_off, const float* __restrict__ w_attn,
    const float* __restrict__ w_val, const float* __restrict__ w_out,
    const float* __restrict__ b_off, const float* __restrict__ b_attn,
    ushort_t* __restrict__ wt_val, ushort_t* __restrict__ wt_qoa,
    ushort_t* __restrict__ wt_out, float* __restrict__ bias_qoa,
    int* __restrict__ counters)
{
  int bid = blockIdx.x;
  int k = threadIdx.x;
  if (bid < 256) {
    int n = bid;
    wt_val[n*KDIM + k] = f2b(w_val[k*256 + n]);
  } else if (bid < 640) {
    int n = bid - 256;
    float v = (n < 256) ? w_off[k*256 + n] : w_attn[k*128 + (n - 256)];
    wt_qoa[n*KDIM + k] = f2b(v);
  } else if (bid < 896) {
    int n = bid - 640;
    wt_out[n*KDIM + k] = f2b(w_out[k*256 + n]);
  } else {
    if (k < 128) counters[k] = 0;   // counters[0] and counters[64] used (separate lines)
    for (int i = k; i < 384; i += 256)
      bias_qoa[i] = (i < 256) ? b_off[i] : b_attn[i - 256];
  }
}

// ---- merged launch, 512-thread blocks (round-6 schedule, FROZEN), with
// vproj operand-swapped MFMA (D[row=n]) -> 8-byte vectorized stores.
// blocks [0,96) = qoa GEMM (256x128 tiles); [96,768) = vproj persistent-B,
// block-level atomic 256-row tile claims (lockstep halves). v_proj stored
// HEAD-MAJOR [b][h][21760][32] bf16 for sampler line efficiency.
__global__ __launch_bounds__(512) void merged_gemms(
    const float* __restrict__ value, const ushort_t* __restrict__ wt_val,
    const float* __restrict__ b_val, ushort_t* __restrict__ v_proj,
    const float* __restrict__ query, const ushort_t* __restrict__ wt_qoa,
    const float* __restrict__ bias_qoa, float* __restrict__ qoa,
    int* __restrict__ counters)
{
  __shared__ __align__(16) char smem[65536];
  __shared__ int s_mt;
  const int tid  = threadIdx.x;
  const int wave = tid >> 6;        // 0..7
  const int lane = tid & 63;
  const int lrow = lane & 15;
  const int quad = lane >> 4;

  if (blockIdx.x < QOA_BLOCKS) {
    // ---------------- qoa GEMM path: 256x128 tile, 8 waves ----------------
    ushort_t* sA = (ushort_t*)smem;                      // 256*72*2 = 36864
    ushort_t* sB = (ushort_t*)(smem + 256 * LDST * 2);   // 128*72*2 = 18432
    const int m0 = (blockIdx.x % 32) * 256;
    const int n0 = (blockIdx.x / 32) * 128;
    const int M = NQ, N = 384;

    f32x4 acc[2][8];
    #pragma unroll
    for (int i = 0; i < 2; ++i)
      #pragma unroll
      for (int j = 0; j < 8; ++j) acc[i][j] = {0.f, 0.f, 0.f, 0.f};

    for (int kc = 0; kc < KDIM; kc += BK) {
      #pragma unroll
      for (int i = 0; i < 8; ++i) {
        int f   = tid + i * 512;
        int row = f >> 4;           // 0..255
        int c4  = f & 15;
        int gr  = m0 + row;
        float4 val = {0.f, 0.f, 0.f, 0.f};
        if (gr < M) val = *(const float4*)(query + (size_t)gr * KDIM + kc + c4 * 4);
        uint2_t t;
        t.x = pack_bf16x2(val.x, val.y);
        t.y = pack_bf16x2(val.z, val.w);
        *(uint2_t*)&sA[row * LDST + c4 * 4] = t;
      }
      #pragma unroll
      for (int i = 0; i < 2; ++i) {
        int f   = tid + i * 512;
        int row = f >> 3;           // 0..127
        int seg = f & 7;
        s16x8 v = *(const s16x8*)(wt_qoa + (size_t)(n0 + row) * KDIM + kc + seg * 8);
        *(s16x8*)&sB[row * LDST + seg * 8] = v;
      }
      __syncthreads();
      #pragma unroll
      for (int ki = 0; ki < BK; ki += 32) {
        int krow = ki + quad * 8;
        s16x8 af[2], bfr[8];
        #pragma unroll
        for (int mt = 0; mt < 2; ++mt)
          af[mt] = *(const s16x8*)&sA[(wave * 32 + mt * 16 + lrow) * LDST + krow];
        #pragma unroll
        for (int nt = 0; nt < 8; ++nt)
          bfr[nt] = *(const s16x8*)&sB[(nt * 16 + lrow) * LDST + krow];
        // swapped operands: D[row=n][col=m] -> vectorized epilogue
        #pragma unroll
        for (int mt = 0; mt < 2; ++mt)
          #pragma unroll
          for (int nt = 0; nt < 8; ++nt)
            acc[mt][nt] = __builtin_amdgcn_mfma_f32_16x16x32_bf16(
                bfr[nt], af[mt], acc[mt][nt], 0, 0, 0);
      }
      __syncthreads();
    }
    // epilogue: lane holds 4 consecutive n -> float4 stores
    #pragma unroll
    for (int mt = 0; mt < 2; ++mt) {
      const int gm = m0 + wave * 32 + mt * 16 + lrow;
      if (gm < M) {
        #pragma unroll
        for (int nt = 0; nt < 8; ++nt) {
          const int gn = n0 + nt * 16 + quad * 4;
          const float4 b4 = *(const float4*)(bias_qoa + gn);
          float4 o = {acc[mt][nt][0] + b4.x, acc[mt][nt][1] + b4.y,
                      acc[mt][nt][2] + b4.z, acc[mt][nt][3] + b4.w};
          *(float4*)(qoa + (size_t)gm * N + gn) = o;
        }
      }
    }
    return;
  }

  // ---------------- vproj path: persistent-B, block-level 256-row tile claims ----------------
  ushort_t* sB = (ushort_t*)smem;   // 128*256*2 = 65536
  const int vbid = blockIdx.x - QOA_BLOCKS;   // 0..671
  const int half = vbid & 1;
  const int n0   = half * 128;

  // stage B-half: 128 rows x 32 chunks(16B); store chunk c at (c ^ (row&7))
  {
    const ushort_t* src = wt_val + (size_t)n0 * KDIM;
    #pragma unroll
    for (int i = 0; i < 8; ++i) {
      int g   = tid + i * 512;
      int row = g >> 5;
      int c   = g & 31;
      s16x8 v = *(const s16x8*)(src + row * KDIM + c * 8);
      *(s16x8*)&sB[row * 256 + ((c ^ (row & 7)) * 8)] = v;
    }
  }
  __syncthreads();

  const int swz = lrow & 7;

  while (true) {
    if (tid == 0) s_mt = atomicAdd(&counters[half * 64], 1);
    __syncthreads();
    const int mt = s_mt;
    if (mt >= VM_TILES2) break;
    const int m0 = mt * 256;
    const int bidx  = mt / 85;            // batch (tiles align: 21760 = 85*256)
    const int rbase = m0 - bidx * 21760;  // local row base within batch
    const float* arow0 = value + (size_t)(m0 + wave * 32 + lrow) * KDIM + quad * 8;
    const float* arow1 = arow0 + 16 * KDIM;

    f32x4 acc[2][8];
    #pragma unroll
    for (int m = 0; m < 2; ++m)
      #pragma unroll
      for (int nt = 0; nt < 8; ++nt) acc[m][nt] = {0.f, 0.f, 0.f, 0.f};

    float4 st[2][2][2];   // [buf][mtile][half]
    st[0][0][0] = *(const float4*)(arow0);
    st[0][0][1] = *(const float4*)(arow0 + 4);
    st[0][1][0] = *(const float4*)(arow1);
    st[0][1][1] = *(const float4*)(arow1 + 4);

    #pragma unroll
    for (int ks = 0; ks < 8; ++ks) {
      const int cur = ks & 1, nxt = cur ^ 1;
      if (ks < 7) {
        const float* p0 = arow0 + (ks + 1) * 32;
        const float* p1 = arow1 + (ks + 1) * 32;
        st[nxt][0][0] = *(const float4*)(p0);
        st[nxt][0][1] = *(const float4*)(p0 + 4);
        st[nxt][1][0] = *(const float4*)(p1);
        st[nxt][1][1] = *(const float4*)(p1 + 4);
      }
      s16x8 af[2];
      #pragma unroll
      for (int m = 0; m < 2; ++m) {
        union { uint4_t d; s16x8 v; } u;
        u.d.x = pack_bf16x2(st[cur][m][0].x, st[cur][m][0].y);
        u.d.y = pack_bf16x2(st[cur][m][0].z, st[cur][m][0].w);
        u.d.z = pack_bf16x2(st[cur][m][1].x, st[cur][m][1].y);
        u.d.w = pack_bf16x2(st[cur][m][1].z, st[cur][m][1].w);
        af[m] = u.v;
      }
      // swapped operands: D[row=n][col=m] -> 8B stores in epilogue
      #pragma unroll
      for (int nt = 0; nt < 8; ++nt) {
        s16x8 bf = *(const s16x8*)&sB[(nt * 16 + lrow) * 256 +
                                      (((4 * ks + quad) ^ swz) * 8)];
        acc[0][nt] = __builtin_amdgcn_mfma_f32_16x16x32_bf16(bf, af[0], acc[0][nt], 0, 0, 0);
        acc[1][nt] = __builtin_amdgcn_mfma_f32_16x16x32_bf16(bf, af[1], acc[1][nt], 0, 0, 0);
      }
    }

    // epilogue: HEAD-MAJOR v_proj[(b*8+h)][rl][d]; lane holds 4 consecutive n
    // (= 4 consecutive d within one head) -> 16x 8-byte stores per lane
    #pragma unroll
    for (int m = 0; m < 2; ++m) {
      const int rl = rbase + wave * 32 + m * 16 + lrow;   // local row in batch
      #pragma unroll
      for (int nt = 0; nt < 8; ++nt) {
        const int gn = n0 + nt * 16 + quad * 4;
        const int h  = gn >> 5;
        const int d  = gn & 31;
        const float4 b4 = *(const float4*)(b_val + gn);
        uint2_t u;
        u.x = pack_bf16x2(acc[m][nt][0] + b4.x, acc[m][nt][1] + b4.y);
        u.y = pack_bf16x2(acc[m][nt][2] + b4.z, acc[m][nt][3] + b4.w);
        *(uint2_t*)(v_proj + (size_t)(bidx * 8 + h) * HL + (size_t)rl * 32 + d) = u;
      }
    }
    __syncthreads();   // protect s_mt before next claim
  }
}

// ---- sampler: wave-per-query (4 q/block, no barriers), head-major v_proj ----
__global__ __launch_bounds__(256) void ms_deform_sample(
    const ushort_t* __restrict__ v,     // [BS][8][21760][32] bf16 (head-major)
    const float* __restrict__ qoa,      // [8000][384]
    const float* __restrict__ refp,     // [8000][4]
    float* __restrict__ outq)           // [8000][256]
{
  __shared__ float s_w[4][512];
  __shared__ int   s_i[4][512];
  const int tid  = threadIdx.x;
  const int wave = tid >> 6;
  const int l    = tid & 63;
  const int bq   = blockIdx.x * 4 + wave;
  const int b    = bq / 1000;

  const float* qrow = qoa + (size_t)bq * 384;
  const float* rp   = refp + (size_t)bq * 4;
  const float rx = rp[0], ry = rp[1], rw = rp[2], rh = rp[3];

  // ---- phase 1 (all 64 lanes): slots s0 = l (heads 0-3), s1 = l+64 (heads 4-7)
  {
    const int p   = l & 15;
    const int lvl = p >> 2;
    const int HWs[4] = {128, 64, 32, 16};
    const int STs[4] = {0, 16384, 20480, 21504};
    const int W = HWs[lvl], H = HWs[lvl], st = STs[lvl];

    float lg0 = qrow[256 + l];
    float lg1 = qrow[256 + 64 + l];
    float m0 = lg0, m1 = lg1;
    #pragma unroll
    for (int s = 8; s >= 1; s >>= 1) {
      m0 = fmaxf(m0, __shfl_xor(m0, s));
      m1 = fmaxf(m1, __shfl_xor(m1, s));
    }
    float e0 = __expf(lg0 - m0), e1 = __expf(lg1 - m1);
    float su0 = e0, su1 = e1;
    #pragma unroll
    for (int s = 8; s >= 1; s >>= 1) {
      su0 += __shfl_xor(su0, s);
      su1 += __shfl_xor(su1, s);
    }
    const float aw0 = e0 / su0, aw1 = e1 / su1;

    #pragma unroll
    for (int half = 0; half < 2; ++half) {
      const int s = l + half * 64;
      const float aw = half ? aw1 : aw0;
      const float ox = qrow[2 * s], oy = qrow[2 * s + 1];
      float x = (rx + ox * 0.125f * rw) * (float)W - 0.5f;
      float y = (ry + oy * 0.125f * rh) * (float)H - 0.5f;
      float x0f = floorf(x), y0f = floorf(y);
      int x0 = (int)x0f, y0 = (int)y0f;
      float fx = x - x0f, fy = y - y0f;
      float wc[4] = {(1.f - fx) * (1.f - fy), fx * (1.f - fy),
                     (1.f - fx) * fy,         fx * fy};
      #pragma unroll
      for (int c = 0; c < 4; ++c) {
        int xi = x0 + (c & 1);
        int yi = y0 + (c >> 1);
        bool valid = (xi >= 0) && (xi < W) && (yi >= 0) && (yi < H);
        int xc = min(max(xi, 0), W - 1);
        int yc = min(max(yi, 0), H - 1);
        s_w[wave][s * 4 + c] = valid ? wc[c] * aw : 0.f;
        s_i[wave][s * 4 + c] = st + yc * W + xc;
      }
    }
  }
  // wave-local: ensure ds_writes land before cross-lane ds_reads
  asm volatile("s_waitcnt lgkmcnt(0)" ::: "memory");

  // ---- phase 2: lane = (h, sub, cpair); 32 gathers in 4 batches of 8
  const int h     = l >> 3;          // 0..7
  const int sub   = (l >> 1) & 3;    // dim octet
  const int cpair = l & 1;           // corners {0,1} or {2,3}
  const ushort_t* vb = v + (size_t)(b * 8 + h) * HL + sub * 8;

  float acc[8];
  #pragma unroll
  for (int d = 0; d < 8; ++d) acc[d] = 0.f;

  #pragma unroll
  for (int batch = 0; batch < 4; ++batch) {
    float wgt[8]; int idx[8];
    #pragma unroll
    for (int u = 0; u < 8; ++u) {
      const int slot = batch * 8 + u;          // 0..31
      const int p  = slot >> 1;
      const int c  = cpair * 2 + (slot & 1);
      const int j  = h * 64 + p * 4 + c;
      wgt[u] = s_w[wave][j];
      idx[u] = s_i[wave][j];
    }
    s16x8 vv[8];
    #pragma unroll
    for (int u = 0; u < 8; ++u)
      vv[u] = *(const s16x8*)(vb + (size_t)idx[u] * 32);
    #pragma unroll
    for (int u = 0; u < 8; ++u)
      #pragma unroll
      for (int d = 0; d < 8; ++d)
        acc[d] += wgt[u] * b2f((ushort_t)vv[u][d]);
  }

  // combine the two corner-pair lanes
  #pragma unroll
  for (int d = 0; d < 8; ++d) acc[d] += __shfl_xor(acc[d], 1);

  if (cpair == 0) {
    float* dst = outq + (size_t)bq * 256 + h * 32 + sub * 8;
    float4 o0 = {acc[0], acc[1], acc[2], acc[3]};
    float4 o1 = {acc[4], acc[5], acc[6], acc[7]};
    *(float4*)dst = o0;
    *(float4*)(dst + 4) = o1;
  }
}

// ---- out-projection GEMM: 64x64 tiles, 500 blocks (2/CU), swapped ops ----
__global__ __launch_bounds__(256) void gemm_bf16(
    const float* __restrict__ A, const ushort_t* __restrict__ Bt,
    const float* __restrict__ bias, float* __restrict__ Cf,
    int M, int N)
{
  __shared__ ushort_t sA[64 * LDST];
  __shared__ ushort_t sB[64 * LDST];
  const int tid  = threadIdx.x;
  const int m0   = blockIdx.x * 64;
  const int n0   = blockIdx.y * 64;
  const int wave = tid >> 6;        // 0..3
  const int lane = tid & 63;
  const int lrow = lane & 15;
  const int quad = lane >> 4;

  f32x4 acc[4];
  #pragma unroll
  for (int j = 0; j < 4; ++j) acc[j] = {0.f, 0.f, 0.f, 0.f};

  for (int kc = 0; kc < KDIM; kc += BK) {
    #pragma unroll
    for (int i = 0; i < 4; ++i) {
      int f   = tid + i * 256;
      int row = f >> 4;          // 0..63
      int c4  = f & 15;
      float4 val = *(const float4*)(A + (size_t)(m0 + row) * KDIM + kc + c4 * 4);
      uint2_t t;
      t.x = pack_bf16x2(val.x, val.y);
      t.y = pack_bf16x2(val.z, val.w);
      *(uint2_t*)&sA[row * LDST + c4 * 4] = t;
    }
    #pragma unroll
    for (int i = 0; i < 2; ++i) {
      int f   = tid + i * 256;
      int row = f >> 3;          // 0..63
      int seg = f & 7;
      s16x8 v = *(const s16x8*)(Bt + (size_t)(n0 + row) * KDIM + kc + seg * 8);
      *(s16x8*)&sB[row * LDST + seg * 8] = v;
    }
    __syncthreads();
    #pragma unroll
    for (int ki = 0; ki < BK; ki += 32) {
      int krow = ki + quad * 8;
      s16x8 af = *(const s16x8*)&sA[(wave * 16 + lrow) * LDST + krow];
      s16x8 bfr[4];
      #pragma unroll
      for (int nt = 0; nt < 4; ++nt)
        bfr[nt] = *(const s16x8*)&sB[(nt * 16 + lrow) * LDST + krow];
      #pragma unroll
      for (int nt = 0; nt < 4; ++nt)
        acc[nt] = __builtin_amdgcn_mfma_f32_16x16x32_bf16(bfr[nt], af, acc[nt], 0, 0, 0);
    }
    __syncthreads();
  }
  // epilogue: lane holds 4 consecutive n -> float4 stores
  {
    const int gm = m0 + wave * 16 + lrow;
    #pragma unroll
    for (int nt = 0; nt < 4; ++nt) {
      const int gn = n0 + nt * 16 + quad * 4;
      const float4 b4 = *(const float4*)(bias + gn);
      float4 o = {acc[nt][0] + b4.x, acc[nt][1] + b4.y,
                  acc[nt][2] + b4.z, acc[nt][3] + b4.w};
      *(float4*)(Cf + (size_t)gm * N + gn) = o;
    }
  }
}

extern "C" void kernel_launch(void* const* d_in, const int* in_sizes, int n_in,
                              void* d_out, int out_size, void* d_ws, size_t ws_size,
                              hipStream_t stream) {
  const float* query  = (const float*)d_in[0];
  const float* refp   = (const float*)d_in[1];
  const float* value  = (const float*)d_in[2];
  const float* w_off  = (const float*)d_in[4];
  const float* b_off  = (const float*)d_in[5];
  const float* w_attn = (const float*)d_in[6];
  const float* b_attn = (const float*)d_in[7];
  const float* w_val  = (const float*)d_in[8];
  const float* b_val  = (const float*)d_in[9];
  const float* w_out  = (const float*)d_in[10];
  const float* b_out  = (const float*)d_in[11];
  float* out = (float*)d_out;

  char* ws = (char*)d_ws;
  const size_t WS_NEEDED = 110069760;
  if (ws_size < WS_NEEDED) return;
  ushort_t* wt_val   = (ushort_t*)(ws);                 // 131072
  ushort_t* wt_qoa   = (ushort_t*)(ws + 131072);        // 196608
  ushort_t* wt_out   = (ushort_t*)(ws + 327680);        // 131072
  float*    bias_qoa = (float*)   (ws + 458752);        // 1536
  int*      counters = (int*)     (ws + 460288);        // 512 (ids 0 and 64 used)
  ushort_t* v_proj   = (ushort_t*)(ws + 460800);        // 89128960 (head-major)
  float*    qoa      = (float*)   (ws + 89589760);      // 12288000
  float*    outq     = (float*)   (ws + 101877760);     // 8192000

  prep_weights<<<897, 256, 0, stream>>>(w_off, w_attn, w_val, w_out, b_off, b_attn,
                                        wt_val, wt_qoa, wt_out, bias_qoa, counters);
  // qoa GEMM (blocks 0..95) + value projection (blocks 96..767), 512-thr blocks
  merged_gemms<<<QOA_BLOCKS + VPROJ_BLOCKS, 512, 0, stream>>>(
      value, wt_val, b_val, v_proj, query, wt_qoa, bias_qoa, qoa, counters);
  // sampling + softmax + weighted sum (wave-per-query, 4 q/block)
  ms_deform_sample<<<NQ / 4, 256, 0, stream>>>(v_proj, qoa, refp, outq);
  // output projection (64x64 tiles, 500 blocks)
  gemm_bf16<<<dim3(125, 4), 256, 0, stream>>>(outq, wt_out, b_out, out, NQ, 256);
}

// Round 11
// 340.486 us; speedup vs baseline: 1.0752x; 1.0752x over previous
//
#include <hip/hip_runtime.h>

typedef unsigned short ushort_t;
typedef short s16x8 __attribute__((ext_vector_type(8)));
typedef float f32x4 __attribute__((ext_vector_type(4)));
typedef unsigned int uint2_t __attribute__((ext_vector_type(2)));
typedef unsigned int uint4_t __attribute__((ext_vector_type(4)));

#define KDIM 256
#define BK 64
#define LDST 72          // 64 + 8 pad (bf16 elems)
#define LV_TOTAL 21760
#define HL 696320        // 21760 * 32 elems per (batch,head) plane
#define NQ 8000
#define VM_TILES_FB 680  // 174080 / 256 (256-row full-width tiles, single counter)
#define QOA_BLOCKS 96    // 32 m-tiles (256 rows) x 3 n-tiles (128 cols)
#define VPROJ_BLOCKS 320 // oversubscribed claim-balanced (1 block/CU at 128KB LDS)

__device__ inline unsigned short f2b(float f) {
  union { float f; unsigned u; } v; v.f = f;
  return (unsigned short)((v.u + 0x7fffu + ((v.u >> 16) & 1u)) >> 16);  // RNE
}
__device__ inline float b2f(unsigned short h) {
  union { unsigned u; float f; } v; v.u = ((unsigned)h) << 16;
  return v.f;
}
// round-half-up bf16 pair pack: 2x v_add_u32 + 1x v_perm_b32
__device__ inline unsigned pack_bf16x2(float lo, float hi) {
  union { float f; unsigned u; } a, b;
  a.f = lo; b.f = hi;
  return __builtin_amdgcn_perm(b.u + 0x8000u, a.u + 0x8000u, 0x07060302u);
}
__device__ inline unsigned short f2b_cheap(float f) {
  union { float f; unsigned u; } v; v.f = f;
  return (unsigned short)((v.u + 0x8000u) >> 16);
}

// ---- weight prep: transpose to [n][k] + bf16 convert; zero tile counters ----
__global__ __launch_bounds__(256) void prep_weights(
    const float* __restrict__ w_off, const float* __restrict__ w_attn,
    const float* __restrict__ w_val, const float* __restrict__ w_out,
    const float* __restrict__ b_off, const float* __restrict__ b_attn,
    ushort_t* __restrict__ wt_val, ushort_t* __restrict__ wt_qoa,
    ushort_t* __restrict__ wt_out, float* __restrict__ bias_qoa,
    int* __restrict__ counters)
{
  int bid = blockIdx.x;
  int k = threadIdx.x;
  if (bid < 256) {
    int n = bid;
    wt_val[n*KDIM + k] = f2b(w_val[k*256 + n]);
  } else if (bid < 640) {
    int n = bid - 256;
    float v = (n < 256) ? w_off[k*256 + n] : w_attn[k*128 + (n - 256)];
    wt_qoa[n*KDIM + k] = f2b(v);
  } else if (bid < 896) {
    int n = bid - 640;
    wt_out[n*KDIM + k] = f2b(w_out[k*256 + n]);
  } else {
    if (k < 128) counters[k] = 0;
    for (int i = k; i < 384; i += 256)
      bias_qoa[i] = (i < 256) ? b_off[i] : b_attn[i - 256];
  }
}

// ---- merged launch, 512-thread blocks, DYNAMIC 128KB LDS:
// blocks [0,96) = qoa GEMM (256x128 tiles, round-7 code unchanged);
// [96,416) = vproj FULL-B persistent (256x256 bf16 in LDS), single-counter
// 256-row full-width tile claims, round-7 claim/barrier/dbuf schedule,
// unswapped MFMA + round-7 scalar head-major epilogue.
__global__ __launch_bounds__(512, 2) void merged_gemms(
    const float* __restrict__ value, const ushort_t* __restrict__ wt_val,
    const float* __restrict__ b_val, ushort_t* __restrict__ v_proj,
    const float* __restrict__ query, const ushort_t* __restrict__ wt_qoa,
    const float* __restrict__ bias_qoa, float* __restrict__ qoa,
    int* __restrict__ counters)
{
  extern __shared__ __align__(16) char smem[];
  __shared__ int s_mt;
  const int tid  = threadIdx.x;
  const int wave = tid >> 6;        // 0..7
  const int lane = tid & 63;
  const int lrow = lane & 15;
  const int quad = lane >> 4;

  if (blockIdx.x < QOA_BLOCKS) {
    // ---------------- qoa GEMM path: 256x128 tile, 8 waves ----------------
    ushort_t* sA = (ushort_t*)smem;                      // 256*72*2 = 36864
    ushort_t* sB = (ushort_t*)(smem + 256 * LDST * 2);   // 128*72*2 = 18432
    const int m0 = (blockIdx.x % 32) * 256;
    const int n0 = (blockIdx.x / 32) * 128;
    const int M = NQ, N = 384;

    f32x4 acc[2][8];
    #pragma unroll
    for (int i = 0; i < 2; ++i)
      #pragma unroll
      for (int j = 0; j < 8; ++j) acc[i][j] = {0.f, 0.f, 0.f, 0.f};

    for (int kc = 0; kc < KDIM; kc += BK) {
      #pragma unroll
      for (int i = 0; i < 8; ++i) {
        int f   = tid + i * 512;
        int row = f >> 4;           // 0..255
        int c4  = f & 15;
        int gr  = m0 + row;
        float4 val = {0.f, 0.f, 0.f, 0.f};
        if (gr < M) val = *(const float4*)(query + (size_t)gr * KDIM + kc + c4 * 4);
        uint2_t t;
        t.x = pack_bf16x2(val.x, val.y);
        t.y = pack_bf16x2(val.z, val.w);
        *(uint2_t*)&sA[row * LDST + c4 * 4] = t;
      }
      #pragma unroll
      for (int i = 0; i < 2; ++i) {
        int f   = tid + i * 512;
        int row = f >> 3;           // 0..127
        int seg = f & 7;
        s16x8 v = *(const s16x8*)(wt_qoa + (size_t)(n0 + row) * KDIM + kc + seg * 8);
        *(s16x8*)&sB[row * LDST + seg * 8] = v;
      }
      __syncthreads();
      #pragma unroll
      for (int ki = 0; ki < BK; ki += 32) {
        int krow = ki + quad * 8;
        s16x8 af[2], bfr[8];
        #pragma unroll
        for (int mt = 0; mt < 2; ++mt)
          af[mt] = *(const s16x8*)&sA[(wave * 32 + mt * 16 + lrow) * LDST + krow];
        #pragma unroll
        for (int nt = 0; nt < 8; ++nt)
          bfr[nt] = *(const s16x8*)&sB[(nt * 16 + lrow) * LDST + krow];
        // swapped operands: D[row=n][col=m] -> vectorized epilogue
        #pragma unroll
        for (int mt = 0; mt < 2; ++mt)
          #pragma unroll
          for (int nt = 0; nt < 8; ++nt)
            acc[mt][nt] = __builtin_amdgcn_mfma_f32_16x16x32_bf16(
                bfr[nt], af[mt], acc[mt][nt], 0, 0, 0);
      }
      __syncthreads();
    }
    // epilogue: lane holds 4 consecutive n -> float4 stores
    #pragma unroll
    for (int mt = 0; mt < 2; ++mt) {
      const int gm = m0 + wave * 32 + mt * 16 + lrow;
      if (gm < M) {
        #pragma unroll
        for (int nt = 0; nt < 8; ++nt) {
          const int gn = n0 + nt * 16 + quad * 4;
          const float4 b4 = *(const float4*)(bias_qoa + gn);
          float4 o = {acc[mt][nt][0] + b4.x, acc[mt][nt][1] + b4.y,
                      acc[mt][nt][2] + b4.z, acc[mt][nt][3] + b4.w};
          *(float4*)(qoa + (size_t)gm * N + gn) = o;
        }
      }
    }
    return;
  }

  // ---------------- vproj path: FULL-B persistent (256x256), single counter ----
  ushort_t* sB = (ushort_t*)smem;   // 256*256*2 = 131072

  // stage full B: 256 rows x 32 chunks(16B); store chunk c at (c ^ (row&7))
  {
    #pragma unroll
    for (int i = 0; i < 16; ++i) {
      int g   = tid + i * 512;
      int row = g >> 5;            // 0..255
      int c   = g & 31;
      s16x8 v = *(const s16x8*)(wt_val + (size_t)row * KDIM + c * 8);
      *(s16x8*)&sB[row * 256 + ((c ^ (row & 7)) * 8)] = v;
    }
  }
  __syncthreads();

  float bv[16];
  #pragma unroll
  for (int nt = 0; nt < 16; ++nt) bv[nt] = b_val[nt * 16 + lrow];

  const int swz = lrow & 7;

  while (true) {
    if (tid == 0) s_mt = atomicAdd(&counters[0], 1);
    __syncthreads();
    const int mt = s_mt;
    if (mt >= VM_TILES_FB) break;
    const int m0 = mt * 256;
    const int bidx  = mt / 85;            // batch (tiles align: 21760 = 85*256)
    const int rbase = m0 - bidx * 21760;  // local row base within batch
    const float* arow0 = value + (size_t)(m0 + wave * 32 + lrow) * KDIM + quad * 8;
    const float* arow1 = arow0 + 16 * KDIM;

    f32x4 acc[2][16];
    #pragma unroll
    for (int m = 0; m < 2; ++m)
      #pragma unroll
      for (int nt = 0; nt < 16; ++nt) acc[m][nt] = {0.f, 0.f, 0.f, 0.f};

    float4 st[2][2][2];   // [buf][mtile][half]
    st[0][0][0] = *(const float4*)(arow0);
    st[0][0][1] = *(const float4*)(arow0 + 4);
    st[0][1][0] = *(const float4*)(arow1);
    st[0][1][1] = *(const float4*)(arow1 + 4);

    #pragma unroll
    for (int ks = 0; ks < 8; ++ks) {
      const int cur = ks & 1, nxt = cur ^ 1;
      if (ks < 7) {
        const float* p0 = arow0 + (ks + 1) * 32;
        const float* p1 = arow1 + (ks + 1) * 32;
        st[nxt][0][0] = *(const float4*)(p0);
        st[nxt][0][1] = *(const float4*)(p0 + 4);
        st[nxt][1][0] = *(const float4*)(p1);
        st[nxt][1][1] = *(const float4*)(p1 + 4);
      }
      s16x8 af[2];
      #pragma unroll
      for (int m = 0; m < 2; ++m) {
        union { uint4_t d; s16x8 v; } u;
        u.d.x = pack_bf16x2(st[cur][m][0].x, st[cur][m][0].y);
        u.d.y = pack_bf16x2(st[cur][m][0].z, st[cur][m][0].w);
        u.d.z = pack_bf16x2(st[cur][m][1].x, st[cur][m][1].y);
        u.d.w = pack_bf16x2(st[cur][m][1].z, st[cur][m][1].w);
        af[m] = u.v;
      }
      #pragma unroll
      for (int nt = 0; nt < 16; ++nt) {
        s16x8 bf = *(const s16x8*)&sB[(nt * 16 + lrow) * 256 +
                                      (((4 * ks + quad) ^ swz) * 8)];
        acc[0][nt] = __builtin_amdgcn_mfma_f32_16x16x32_bf16(af[0], bf, acc[0][nt], 0, 0, 0);
        acc[1][nt] = __builtin_amdgcn_mfma_f32_16x16x32_bf16(af[1], bf, acc[1][nt], 0, 0, 0);
      }
    }

    // epilogue: HEAD-MAJOR v_proj[(b*8+h)][rl][d] (round-7 scalar pattern)
    #pragma unroll
    for (int m = 0; m < 2; ++m) {
      int rl = rbase + wave * 32 + m * 16 + quad * 4;   // local row in batch
      #pragma unroll
      for (int nt = 0; nt < 16; ++nt) {
        int gn = nt * 16 + lrow;
        int h  = gn >> 5;
        int d  = gn & 31;
        ushort_t* dst = v_proj + (size_t)(bidx * 8 + h) * HL + (size_t)rl * 32 + d;
        #pragma unroll
        for (int r = 0; r < 4; ++r)
          dst[r * 32] = f2b_cheap(acc[m][nt][r] + bv[nt]);
      }
    }
    __syncthreads();   // protect s_mt before next claim
  }
}

// ---- sampler: wave-per-query (4 q/block, no barriers), head-major v_proj ----
__global__ __launch_bounds__(256) void ms_deform_sample(
    const ushort_t* __restrict__ v,     // [BS][8][21760][32] bf16 (head-major)
    const float* __restrict__ qoa,      // [8000][384]
    const float* __restrict__ refp,     // [8000][4]
    float* __restrict__ outq)           // [8000][256]
{
  __shared__ float s_w[4][512];
  __shared__ int   s_i[4][512];
  const int tid  = threadIdx.x;
  const int wave = tid >> 6;
  const int l    = tid & 63;
  const int bq   = blockIdx.x * 4 + wave;
  const int b    = bq / 1000;

  const float* qrow = qoa + (size_t)bq * 384;
  const float* rp   = refp + (size_t)bq * 4;
  const float rx = rp[0], ry = rp[1], rw = rp[2], rh = rp[3];

  // ---- phase 1 (all 64 lanes): slots s0 = l (heads 0-3), s1 = l+64 (heads 4-7)
  {
    const int p   = l & 15;
    const int lvl = p >> 2;
    const int HWs[4] = {128, 64, 32, 16};
    const int STs[4] = {0, 16384, 20480, 21504};
    const int W = HWs[lvl], H = HWs[lvl], st = STs[lvl];

    float lg0 = qrow[256 + l];
    float lg1 = qrow[256 + 64 + l];
    float m0 = lg0, m1 = lg1;
    #pragma unroll
    for (int s = 8; s >= 1; s >>= 1) {
      m0 = fmaxf(m0, __shfl_xor(m0, s));
      m1 = fmaxf(m1, __shfl_xor(m1, s));
    }
    float e0 = __expf(lg0 - m0), e1 = __expf(lg1 - m1);
    float su0 = e0, su1 = e1;
    #pragma unroll
    for (int s = 8; s >= 1; s >>= 1) {
      su0 += __shfl_xor(su0, s);
      su1 += __shfl_xor(su1, s);
    }
    const float aw0 = e0 / su0, aw1 = e1 / su1;

    #pragma unroll
    for (int half = 0; half < 2; ++half) {
      const int s = l + half * 64;
      const float aw = half ? aw1 : aw0;
      const float ox = qrow[2 * s], oy = qrow[2 * s + 1];
      float x = (rx + ox * 0.125f * rw) * (float)W - 0.5f;
      float y = (ry + oy * 0.125f * rh) * (float)H - 0.5f;
      float x0f = floorf(x), y0f = floorf(y);
      int x0 = (int)x0f, y0 = (int)y0f;
      float fx = x - x0f, fy = y - y0f;
      float wc[4] = {(1.f - fx) * (1.f - fy), fx * (1.f - fy),
                     (1.f - fx) * fy,         fx * fy};
      #pragma unroll
      for (int c = 0; c < 4; ++c) {
        int xi = x0 + (c & 1);
        int yi = y0 + (c >> 1);
        bool valid = (xi >= 0) && (xi < W) && (yi >= 0) && (yi < H);
        int xc = min(max(xi, 0), W - 1);
        int yc = min(max(yi, 0), H - 1);
        s_w[wave][s * 4 + c] = valid ? wc[c] * aw : 0.f;
        s_i[wave][s * 4 + c] = st + yc * W + xc;
      }
    }
  }
  // wave-local: ensure ds_writes land before cross-lane ds_reads
  asm volatile("s_waitcnt lgkmcnt(0)" ::: "memory");

  // ---- phase 2: lane = (h, sub, cpair); 32 gathers in 4 batches of 8
  const int h     = l >> 3;          // 0..7
  const int sub   = (l >> 1) & 3;    // dim octet
  const int cpair = l & 1;           // corners {0,1} or {2,3}
  const ushort_t* vb = v + (size_t)(b * 8 + h) * HL + sub * 8;

  float acc[8];
  #pragma unroll
  for (int d = 0; d < 8; ++d) acc[d] = 0.f;

  #pragma unroll
  for (int batch = 0; batch < 4; ++batch) {
    float wgt[8]; int idx[8];
    #pragma unroll
    for (int u = 0; u < 8; ++u) {
      const int slot = batch * 8 + u;          // 0..31
      const int p  = slot >> 1;
      const int c  = cpair * 2 + (slot & 1);
      const int j  = h * 64 + p * 4 + c;
      wgt[u] = s_w[wave][j];
      idx[u] = s_i[wave][j];
    }
    s16x8 vv[8];
    #pragma unroll
    for (int u = 0; u < 8; ++u)
      vv[u] = *(const s16x8*)(vb + (size_t)idx[u] * 32);
    #pragma unroll
    for (int u = 0; u < 8; ++u)
      #pragma unroll
      for (int d = 0; d < 8; ++d)
        acc[d] += wgt[u] * b2f((ushort_t)vv[u][d]);
  }

  // combine the two corner-pair lanes
  #pragma unroll
  for (int d = 0; d < 8; ++d) acc[d] += __shfl_xor(acc[d], 1);

  if (cpair == 0) {
    float* dst = outq + (size_t)bq * 256 + h * 32 + sub * 8;
    float4 o0 = {acc[0], acc[1], acc[2], acc[3]};
    float4 o1 = {acc[4], acc[5], acc[6], acc[7]};
    *(float4*)dst = o0;
    *(float4*)(dst + 4) = o1;
  }
}

// ---- out-projection GEMM: 64x64 tiles, 500 blocks (2/CU), swapped ops ----
__global__ __launch_bounds__(256) void gemm_bf16(
    const float* __restrict__ A, const ushort_t* __restrict__ Bt,
    const float* __restrict__ bias, float* __restrict__ Cf,
    int M, int N)
{
  __shared__ ushort_t sA[64 * LDST];
  __shared__ ushort_t sB[64 * LDST];
  const int tid  = threadIdx.x;
  const int m0   = blockIdx.x * 64;
  const int n0   = blockIdx.y * 64;
  const int wave = tid >> 6;        // 0..3
  const int lane = tid & 63;
  const int lrow = lane & 15;
  const int quad = lane >> 4;

  f32x4 acc[4];
  #pragma unroll
  for (int j = 0; j < 4; ++j) acc[j] = {0.f, 0.f, 0.f, 0.f};

  for (int kc = 0; kc < KDIM; kc += BK) {
    #pragma unroll
    for (int i = 0; i < 4; ++i) {
      int f   = tid + i * 256;
      int row = f >> 4;          // 0..63
      int c4  = f & 15;
      float4 val = *(const float4*)(A + (size_t)(m0 + row) * KDIM + kc + c4 * 4);
      uint2_t t;
      t.x = pack_bf16x2(val.x, val.y);
      t.y = pack_bf16x2(val.z, val.w);
      *(uint2_t*)&sA[row * LDST + c4 * 4] = t;
    }
    #pragma unroll
    for (int i = 0; i < 2; ++i) {
      int f   = tid + i * 256;
      int row = f >> 3;          // 0..63
      int seg = f & 7;
      s16x8 v = *(const s16x8*)(Bt + (size_t)(n0 + row) * KDIM + kc + seg * 8);
      *(s16x8*)&sB[row * LDST + seg * 8] = v;
    }
    __syncthreads();
    #pragma unroll
    for (int ki = 0; ki < BK; ki += 32) {
      int krow = ki + quad * 8;
      s16x8 af = *(const s16x8*)&sA[(wave * 16 + lrow) * LDST + krow];
      s16x8 bfr[4];
      #pragma unroll
      for (int nt = 0; nt < 4; ++nt)
        bfr[nt] = *(const s16x8*)&sB[(nt * 16 + lrow) * LDST + krow];
      #pragma unroll
      for (int nt = 0; nt < 4; ++nt)
        acc[nt] = __builtin_amdgcn_mfma_f32_16x16x32_bf16(bfr[nt], af, acc[nt], 0, 0, 0);
    }
    __syncthreads();
  }
  // epilogue: lane holds 4 consecutive n -> float4 stores
  {
    const int gm = m0 + wave * 16 + lrow;
    #pragma unroll
    for (int nt = 0; nt < 4; ++nt) {
      const int gn = n0 + nt * 16 + quad * 4;
      const float4 b4 = *(const float4*)(bias + gn);
      float4 o = {acc[nt][0] + b4.x, acc[nt][1] + b4.y,
                  acc[nt][2] + b4.z, acc[nt][3] + b4.w};
      *(float4*)(Cf + (size_t)gm * N + gn) = o;
    }
  }
}

extern "C" void kernel_launch(void* const* d_in, const int* in_sizes, int n_in,
                              void* d_out, int out_size, void* d_ws, size_t ws_size,
                              hipStream_t stream) {
  const float* query  = (const float*)d_in[0];
  const float* refp   = (const float*)d_in[1];
  const float* value  = (const float*)d_in[2];
  const float* w_off  = (const float*)d_in[4];
  const float* b_off  = (const float*)d_in[5];
  const float* w_attn = (const float*)d_in[6];
  const float* b_attn = (const float*)d_in[7];
  const float* w_val  = (const float*)d_in[8];
  const float* b_val  = (const float*)d_in[9];
  const float* w_out  = (const float*)d_in[10];
  const float* b_out  = (const float*)d_in[11];
  float* out = (float*)d_out;

  char* ws = (char*)d_ws;
  const size_t WS_NEEDED = 110069760;
  if (ws_size < WS_NEEDED) return;
  ushort_t* wt_val   = (ushort_t*)(ws);                 // 131072
  ushort_t* wt_qoa   = (ushort_t*)(ws + 131072);        // 196608
  ushort_t* wt_out   = (ushort_t*)(ws + 327680);        // 131072
  float*    bias_qoa = (float*)   (ws + 458752);        // 1536
  int*      counters = (int*)     (ws + 460288);        // 512 (id 0 used)
  ushort_t* v_proj   = (ushort_t*)(ws + 460800);        // 89128960 (head-major)
  float*    qoa      = (float*)   (ws + 89589760);      // 12288000
  float*    outq     = (float*)   (ws + 101877760);     // 8192000

  // allow 128KB dynamic LDS for the merged kernel (full-B vproj).
  // unconditional + checked: non-stream API, legal during graph capture.
  (void)hipFuncSetAttribute((const void*)merged_gemms,
                            hipFuncAttributeMaxDynamicSharedMemorySize, 131072);

  prep_weights<<<897, 256, 0, stream>>>(w_off, w_attn, w_val, w_out, b_off, b_attn,
                                        wt_val, wt_qoa, wt_out, bias_qoa, counters);
  // qoa GEMM (blocks 0..95) + value projection (blocks 96..415), 128KB dyn LDS
  merged_gemms<<<QOA_BLOCKS + VPROJ_BLOCKS, 512, 131072, stream>>>(
      value, wt_val, b_val, v_proj, query, wt_qoa, bias_qoa, qoa, counters);
  // sampling + softmax + weighted sum (wave-per-query, 4 q/block)
  ms_deform_sample<<<NQ / 4, 256, 0, stream>>>(v_proj, qoa, refp, outq);
  // output projection (64x64 tiles, 500 blocks)
  gemm_bf16<<<dim3(125, 4), 256, 0, stream>>>(outq, wt_out, b_out, out, NQ, 256);
}